// Round 21
// baseline (379.112 us; speedup 1.0000x reference)
//
#include <hip/hip_runtime.h>
#include <hip/hip_bf16.h>

// Problem constants
#define HIDDEN   2048
#define N_HEADS  16
#define N_KV     8
#define HEAD_DIM 128
#define SEQ      2048
#define EPS      1e-6f

// MFMA GEMM tile params (m97 structure: 128x128 tile, BK=32, linear LDS)
#define BM 128
#define BN 128
#define BK 32

// MFMA attention tile params
#define ATQ 64
#define ATK 64
#define QKS 136       // Ks row stride in bf16 (128 data + 8 pad)
#define VTS 72        // Vt/Ps row stride in bf16 (64 data + 8 pad)
#define NBX 48        // blocks per head: 16*1 + 16*2 = 48 (CHUNK=16 split-K, v1)

typedef __hip_bfloat16 bf16;
typedef __bf16  bf16x8 __attribute__((ext_vector_type(8)));
typedef short   short8 __attribute__((ext_vector_type(8)));
typedef short   short4v __attribute__((ext_vector_type(4)));
typedef float   f32x4  __attribute__((ext_vector_type(4)));

typedef __attribute__((address_space(1))) void gvoid;
typedef __attribute__((address_space(3))) void lvoid;

// async 16B global->LDS (direct-to-LDS DMA; dest is wave-uniform base + lane*16)
#define ASYNC16(g, l) \
    __builtin_amdgcn_global_load_lds((gvoid*)(g), (lvoid*)(l), 16, 0, 0)

__device__ __forceinline__ short f2bfbits(float x) {
    union { bf16 h; short s; } u;
    u.h = __float2bfloat16(x);
    return u.s;
}

// -------------------- fp32 -> bf16 convert (pure BW) --------------------
__global__ __launch_bounds__(256) void cvt_bf16(const float4* __restrict__ src,
                                                short4v* __restrict__ dst, int n4) {
    const int i = blockIdx.x * 256 + threadIdx.x;
    if (i >= n4) return;
    const float4 v = src[i];
    short4v p;
    p[0] = f2bfbits(v.x); p[1] = f2bfbits(v.y);
    p[2] = f2bfbits(v.z); p[3] = f2bfbits(v.w);
    dst[i] = p;
}

// -------------------- bf16 MFMA GEMM core (m97 structure) --------------------
// C[m][n] = sum_k A[m][k]*B[n][k]; A,B bf16 row-major (stride K).
// MODE 0: C fp32 row-major (stride ldc). MODE 1: C^T bf16 at Ct[n*ldc + m].
// 128x128 tile, BK=32, 256 threads (2x2 waves). Staging via global_load_lds
// width=16 into LINEAR [128][32] LDS. MFMA 16x16x32: A[m=lane&15][k=(lane>>4)*8+j];
// C/D col=lane&15, row=(lane>>4)*4+reg  [m89/m91-verified].
template <int MODE>
__device__ __forceinline__ void gemm_bf(const bf16* __restrict__ A,
                                        const bf16* __restrict__ B,
                                        float* __restrict__ C,
                                        bf16* __restrict__ Ct,
                                        int K, int ldc, int bm, int bn) {
    __shared__ __align__(16) short As[BM * BK];
    __shared__ __align__(16) short Bs[BN * BK];
    const int tid  = threadIdx.x;
    const int lane = tid & 63;
    const int wave = tid >> 6;
    const int wy   = wave & 1;
    const int wx   = wave >> 1;
    const int lrow = lane & 15;
    const int lk   = lane >> 4;
    const int srow = tid >> 2;        // staging row within a 64-row round
    const int scol = (tid & 3) * 8;   // staging col (bf16 units), 16B granules

    f32x4 acc[4][4] = {};

    for (int k0 = 0; k0 < K; k0 += BK) {
        #pragma unroll
        for (int r = 0; r < 2; r++) {
            const int row = r * 64 + srow;
            ASYNC16(&A[(size_t)(bm + row) * K + k0 + scol],
                    &As[(r * 64 + wave * 16) * BK]);
            ASYNC16(&B[(size_t)(bn + row) * K + k0 + scol],
                    &Bs[(r * 64 + wave * 16) * BK]);
        }
        __syncthreads();   // compiler drains vmcnt before s_barrier

        short8 af[4], bfr[4];
        #pragma unroll
        for (int i = 0; i < 4; i++) {
            af[i]  = *(const short8*)&As[(wy * 64 + i * 16 + lrow) * BK + lk * 8];
            bfr[i] = *(const short8*)&Bs[(wx * 64 + i * 16 + lrow) * BK + lk * 8];
        }
        #pragma unroll
        for (int i = 0; i < 4; i++)
            #pragma unroll
            for (int j = 0; j < 4; j++)
                acc[i][j] = __builtin_amdgcn_mfma_f32_16x16x32_bf16(
                    __builtin_bit_cast(bf16x8, af[i]),
                    __builtin_bit_cast(bf16x8, bfr[j]), acc[i][j], 0, 0, 0);
        __syncthreads();
    }

    #pragma unroll
    for (int i = 0; i < 4; i++)
        #pragma unroll
        for (int j = 0; j < 4; j++) {
            if (MODE == 0) {
                #pragma unroll
                for (int v = 0; v < 4; v++)
                    C[(size_t)(bm + wy * 64 + i * 16 + lk * 4 + v) * ldc
                      + bn + wx * 64 + j * 16 + lrow] = acc[i][j][v];
            } else {
                short4v pk;
                #pragma unroll
                for (int v = 0; v < 4; v++) pk[v] = f2bfbits(acc[i][j][v]);
                *(short4v*)&Ct[(size_t)(bn + wx * 64 + j * 16 + lrow) * ldc
                               + bm + wy * 64 + i * 16 + lk * 4] = pk;
            }
        }
}

// Fused Q/K/V projection: grid (16, 32). by<16 -> Q, <24 -> K, else V^T(bf16).
__global__ __launch_bounds__(256) void qkv_mfma(const bf16* __restrict__ x,
                                                const bf16* __restrict__ wq,
                                                const bf16* __restrict__ wk,
                                                const bf16* __restrict__ wv,
                                                float* __restrict__ Q,
                                                float* __restrict__ Kc,
                                                bf16* __restrict__ Vt) {
    const int by = blockIdx.y;
    const int bm = blockIdx.x * 128;
    if (by < 16)
        gemm_bf<0>(x, wq, Q, nullptr, HIDDEN, 2048, bm, by * 128);
    else if (by < 24)
        gemm_bf<0>(x, wk, Kc, nullptr, HIDDEN, 1024, bm, (by - 16) * 128);
    else
        gemm_bf<1>(x, wv, nullptr, Vt, HIDDEN, SEQ, bm, (by - 24) * 128);
}

__global__ __launch_bounds__(256) void oproj_mfma(const bf16* __restrict__ ctx,
                                                  const bf16* __restrict__ wo,
                                                  float* __restrict__ out) {
    gemm_bf<0>(ctx, wo, out, nullptr, N_HEADS * HEAD_DIM, HIDDEN,
               blockIdx.x * 128, blockIdx.y * 128);
}

// -------------------- RoPE + RMSNorm (wave-per-row, barrier-free) ------------
// Lane l owns the RoPE pair (d=l, d=l+64): same cos/sin, no cross-lane data.
// grid (S, 6), 256 threads = 4 waves; wave -> one (s, h) row, h = by*4 + wave.
__global__ __launch_bounds__(256) void rope_norm_kernel(
        const float* __restrict__ Q, const float* __restrict__ K,
        bf16* __restrict__ Qbf, bf16* __restrict__ Kbf,
        const float* __restrict__ qw, const float* __restrict__ kw) {
    const int s = blockIdx.x;
    const int h = blockIdx.y * 4 + (threadIdx.x >> 6);
    const int l = threadIdx.x & 63;

    const float* src;
    const float* w;
    if (h < N_HEADS) { src = Q + (size_t)s * (N_HEADS * HEAD_DIM) + h * HEAD_DIM; w = qw; }
    else             { src = K + (size_t)s * (N_KV * HEAD_DIM) + (h - N_HEADS) * HEAD_DIM; w = kw; }

    const float x1 = src[l];
    const float x2 = src[l + 64];
    const float inv_freq = exp2f((float)l * (-19.931568569324174f / 64.0f));
    const float ang = (float)s * inv_freq;
    float sn, cs;
    __sincosf(ang, &sn, &cs);
    float r1 = x1 * cs - x2 * sn;
    float r2 = x2 * cs + x1 * sn;

    float ss = r1 * r1 + r2 * r2;
    #pragma unroll
    for (int off = 1; off < 64; off <<= 1)
        ss += __shfl_xor(ss, off, 64);
    const float rs = rsqrtf(ss / 128.0f + EPS);

    if (h < N_HEADS) {
        bf16* dst = Qbf + ((size_t)s * N_HEADS + h) * HEAD_DIM;
        dst[l]      = __float2bfloat16(w[l] * r1 * rs);
        dst[l + 64] = __float2bfloat16(w[l + 64] * r2 * rs);
    } else {
        bf16* dst = Kbf + ((size_t)s * N_KV + (h - N_HEADS)) * HEAD_DIM;
        dst[l]      = __float2bfloat16(w[l] * r1 * rs);
        dst[l + 64] = __float2bfloat16(w[l + 64] * r2 * rs);
    }
}

// -------------------- MFMA flash attention, split-K v5 (= measured v1) ------
// REVERT to the best measured mapping (Round 3: 84.8us): grid (48, 16 heads),
// CHUNK=16 K-tiles; bx<16 -> 1 chunk (qtile=bx), else 2 chunks ([0,16) and
// [16,qtile]). 768 blocks = exactly 3/CU (LDS 45KB), all co-resident, max 16
// iters. v2 (V-from-global), v3 (CHT=11+backfill), v4 (LPT order) all measured
// WORSE (134/100/97us) - scheduling theories refuted; v1's all-resident
// no-queue configuration wins. Kept from v3/v4 (validated twice, semantics-
// preserving): diagonal-only masking; deferred l-sum lane reduction.
__global__ __launch_bounds__(256) void attn_split(const bf16* __restrict__ QC,
                                                  const bf16* __restrict__ KbfG,
                                                  const bf16* __restrict__ VtG,
                                                  float* __restrict__ Opart,
                                                  float* __restrict__ Ml) {
    const int h  = blockIdx.y;
    const int bx = blockIdx.x;        // 0..47
    int qtile, t0, t1;
    if (bx < 16)      { qtile = bx;                 t0 = 0;  t1 = qtile; }
    else { const int idx = bx - 16; qtile = 16 + (idx >> 1);
           if (idx & 1) { t0 = 16; t1 = qtile; } else { t0 = 0; t1 = 15; } }
    const int q0    = qtile * ATQ;
    const int kvh   = h >> 1;
    const int tid   = threadIdx.x;
    const int lane  = tid & 63;
    const int w     = tid >> 6;
    const int lrow  = lane & 15;
    const int lk    = lane >> 4;     // quad
    const float scale = 0.08838834764831845f;

    __shared__ short Ks[ATK * QKS];
    __shared__ short Vt[HEAD_DIM * VTS];
    __shared__ short Ps[ATQ * VTS];

    f32x4 O[8] = {};
    float m_run[4] = {-1e30f, -1e30f, -1e30f, -1e30f};
    float l_part[4] = {};            // per-lane partial sums (reduced in epilogue)

    // Q frags straight to registers (bf16)
    short8 aq[4];
    {
        const bf16* qrow =
            &QC[(size_t)(q0 + w * 16 + lrow) * (N_HEADS * HEAD_DIM) + h * HEAD_DIM];
        #pragma unroll
        for (int kc = 0; kc < 4; kc++)
            aq[kc] = *(const short8*)&qrow[kc * 32 + lk * 8];
    }

    for (int t = t0; t <= t1; t++) {
        const int k0 = t * ATK;
        // stage K and Vt (bf16 copies; shared by all 4 waves)
        for (int idx = tid; idx < ATK * 16; idx += 256) {
            const int r = idx >> 4, c8 = idx & 15;
            *(short8*)&Ks[r * QKS + c8 * 8] = *(const short8*)
                &KbfG[((size_t)(k0 + r) * N_KV + kvh) * HEAD_DIM + c8 * 8];
        }
        for (int idx = tid; idx < HEAD_DIM * 8; idx += 256) {
            const int d = idx >> 3, ck = idx & 7;
            *(short8*)&Vt[d * VTS + ck * 8] =
                *(const short8*)&VtG[((size_t)kvh * HEAD_DIM + d) * SEQ + k0 + ck * 8];
        }
        __syncthreads();

        // QK^T: S (16q x 64k) per wave
        f32x4 s[4] = {};
        #pragma unroll
        for (int nt = 0; nt < 4; nt++)
            #pragma unroll
            for (int kc = 0; kc < 4; kc++) {
                const short8 bk = *(const short8*)
                    &Ks[(nt * 16 + lrow) * QKS + kc * 32 + lk * 8];
                s[nt] = __builtin_amdgcn_mfma_f32_16x16x32_bf16(
                    __builtin_bit_cast(bf16x8, aq[kc]),
                    __builtin_bit_cast(bf16x8, bk), s[nt], 0, 0, 0);
            }

        // online softmax (rows q = q0 + 16w + 4*lk + r)
        float p[4][4];
        float mloc[4] = {-1e30f, -1e30f, -1e30f, -1e30f};
        if (t == qtile) {          // diagonal tile: causal mask needed
            #pragma unroll
            for (int nt = 0; nt < 4; nt++) {
                const int kglob = k0 + nt * 16 + lrow;
                #pragma unroll
                for (int r = 0; r < 4; r++) {
                    float v = s[nt][r] * scale;
                    v = (kglob <= q0 + w * 16 + lk * 4 + r) ? v : -1e30f;
                    p[nt][r] = v;
                    mloc[r] = fmaxf(mloc[r], v);
                }
            }
        } else {                   // interior tile: all keys valid
            #pragma unroll
            for (int nt = 0; nt < 4; nt++)
                #pragma unroll
                for (int r = 0; r < 4; r++) {
                    const float v = s[nt][r] * scale;
                    p[nt][r] = v;
                    mloc[r] = fmaxf(mloc[r], v);
                }
        }
        #pragma unroll
        for (int off = 1; off < 16; off <<= 1)
            #pragma unroll
            for (int r = 0; r < 4; r++)
                mloc[r] = fmaxf(mloc[r], __shfl_xor(mloc[r], off, 64));

        float alpha[4];
        #pragma unroll
        for (int r = 0; r < 4; r++) {
            const float mnew = fmaxf(m_run[r], mloc[r]);
            alpha[r] = __expf(m_run[r] - mnew);
            m_run[r] = mnew;
        }
        float es[4] = {};
        #pragma unroll
        for (int nt = 0; nt < 4; nt++)
            #pragma unroll
            for (int r = 0; r < 4; r++) {
                const float e = __expf(p[nt][r] - m_run[r]);
                Ps[(w * 16 + lk * 4 + r) * VTS + nt * 16 + lrow] = f2bfbits(e);
                es[r] += e;
            }
        #pragma unroll
        for (int r = 0; r < 4; r++)
            l_part[r] = l_part[r] * alpha[r] + es[r];
        #pragma unroll
        for (int dnt = 0; dnt < 8; dnt++)
            #pragma unroll
            for (int r = 0; r < 4; r++)
                O[dnt][r] *= alpha[r];

        __syncthreads();   // Ps visible

        // PV: O (16q x 128d) += P (16x64) * V (64x128)
        short8 pa[2];
        #pragma unroll
        for (int ks = 0; ks < 2; ks++)
            pa[ks] = *(const short8*)&Ps[(w * 16 + lrow) * VTS + ks * 32 + lk * 8];
        #pragma unroll
        for (int dnt = 0; dnt < 8; dnt++)
            #pragma unroll
            for (int ks = 0; ks < 2; ks++) {
                const short8 vb = *(const short8*)
                    &Vt[(dnt * 16 + lrow) * VTS + ks * 32 + lk * 8];
                O[dnt] = __builtin_amdgcn_mfma_f32_16x16x32_bf16(
                    __builtin_bit_cast(bf16x8, pa[ks]),
                    __builtin_bit_cast(bf16x8, vb), O[dnt], 0, 0, 0);
            }
        __syncthreads();   // tiles consumed before next staging
    }

    // deferred l-sum reduction over the 16 lrow lanes (exact: alpha was uniform)
    #pragma unroll
    for (int off = 1; off < 16; off <<= 1)
        #pragma unroll
        for (int r = 0; r < 4; r++)
            l_part[r] += __shfl_xor(l_part[r], off, 64);

    // epilogue: write UNNORMALIZED partial O (fp32) + (m,l) per row
    const int slot = h * NBX + bx;
    #pragma unroll
    for (int r = 0; r < 4; r++) {
        const int row = w * 16 + lk * 4 + r;
        float* orow = &Opart[(size_t)slot * (ATQ * HEAD_DIM) + row * HEAD_DIM];
        #pragma unroll
        for (int dnt = 0; dnt < 8; dnt++)
            orow[dnt * 16 + lrow] = O[dnt][r];
        if (lrow == 0) {
            Ml[slot * (ATQ * 2) + row * 2]     = m_run[r];
            Ml[slot * (ATQ * 2) + row * 2 + 1] = l_part[r];
        }
    }
}

// Combine <=2 chunks per (h, s-row), normalize, write ctx bf16 into Qbf.
// grid (256, 16): block handles 8 s-rows; 32 lanes/row, float4 per lane.
__global__ __launch_bounds__(256) void attn_combine(const float* __restrict__ Opart,
                                                    const float* __restrict__ Ml,
                                                    bf16* __restrict__ Qbf) {
    const int h   = blockIdx.y;
    const int s   = blockIdx.x * 8 + (threadIdx.x >> 5);
    const int d   = (threadIdx.x & 31) * 4;
    const int qt  = s >> 6;
    const int row = s & 63;

    int slot0, nch;
    if (qt < 16) { slot0 = h * NBX + qt;                 nch = 1; }
    else         { slot0 = h * NBX + 16 + 2 * (qt - 16); nch = 2; }

    float M = Ml[slot0 * (ATQ * 2) + row * 2];
    float L = Ml[slot0 * (ATQ * 2) + row * 2 + 1];
    float4 o = *(const float4*)&Opart[(size_t)slot0 * (ATQ * HEAD_DIM)
                                      + row * HEAD_DIM + d];
    for (int c = 1; c < nch; c++) {
        const float mc = Ml[(slot0 + c) * (ATQ * 2) + row * 2];
        const float lc = Ml[(slot0 + c) * (ATQ * 2) + row * 2 + 1];
        const float4 oc = *(const float4*)&Opart[(size_t)(slot0 + c) * (ATQ * HEAD_DIM)
                                                 + row * HEAD_DIM + d];
        const float Mn = fmaxf(M, mc);
        const float e0 = __expf(M - Mn);
        const float e1 = __expf(mc - Mn);
        L = L * e0 + lc * e1;
        o.x = o.x * e0 + oc.x * e1;
        o.y = o.y * e0 + oc.y * e1;
        o.z = o.z * e0 + oc.z * e1;
        o.w = o.w * e0 + oc.w * e1;
        M = Mn;
    }
    const float inv = 1.0f / L;
    short4v pk;
    pk[0] = f2bfbits(o.x * inv); pk[1] = f2bfbits(o.y * inv);
    pk[2] = f2bfbits(o.z * inv); pk[3] = f2bfbits(o.w * inv);
    *(short4v*)&Qbf[((size_t)s * N_HEADS + h) * HEAD_DIM + d] = pk;
}

extern "C" void kernel_launch(void* const* d_in, const int* in_sizes, int n_in,
                              void* d_out, int out_size, void* d_ws, size_t ws_size,
                              hipStream_t stream) {
    const float* x   = (const float*)d_in[0]; // [S][HIDDEN] fp32
    const float* wq  = (const float*)d_in[3]; // [2048][2048]
    const float* wk  = (const float*)d_in[4]; // [1024][2048]
    const float* wv  = (const float*)d_in[5]; // [1024][2048]
    const float* wo  = (const float*)d_in[6]; // [2048][2048]
    const float* qnw = (const float*)d_in[7]; // [128]
    const float* knw = (const float*)d_in[8]; // [128]

    // Memory plan (ws >= 48MB):
    //   ws  [ 0,16): Q fp32 proj output (dead after rope)  }
    //   ws  [16,24): x bf16 (dead after qkv)               } Opart 24MB (768 slots)
    //   ws  [24,28): wk bf16 (dead after qkv)              } at attn time
    //   ws  [28,32): wv bf16 (dead after qkv)
    //   ws  [32,40): wq bf16 (dead after qkv) -> Qbf post-rope [S][16][128];
    //                ctx bf16 overwrites in place (combine output)
    //   ws  [40,48): wo bf16 (cvt after qkv; LIVE through oproj)
    //   d_out[0, 8): K fp32 pre-rope (dead after rope) -> Ml (393KB) at attn
    //   d_out[8,12): V^T bf16 [8*128][2048]  } dead before oproj
    //   d_out[12,16): K bf16 post-rope       } oproj output overwrites d_out
    char*  ws    = (char*)d_ws;
    float* Qw    = (float*)ws;
    bf16*  xbf   = (bf16*)(ws + (16u << 20));
    bf16*  wkbf  = (bf16*)(ws + (24u << 20));
    bf16*  wvbf  = (bf16*)(ws + (28u << 20));
    bf16*  wqbf  = (bf16*)(ws + (32u << 20));
    bf16*  Qbf   = (bf16*)(ws + (32u << 20));   // over dead wqbf
    bf16*  wobf  = (bf16*)(ws + (40u << 20));
    float* Opart = (float*)ws;                  // 768 * 32KB = 24MB in [0,24)
    float* Kb    = (float*)d_out;
    float* Ml    = (float*)d_out;               // 393KB over dead Kb
    bf16*  VtG   = (bf16*)((char*)d_out + (8u << 20));
    bf16*  KbfG  = (bf16*)((char*)d_out + (12u << 20));

    // 0) fp32 -> bf16 converts (x + qkv weights)
    cvt_bf16<<<4096, 256, 0, stream>>>((const float4*)x,  (short4v*)xbf,  1048576);
    cvt_bf16<<<4096, 256, 0, stream>>>((const float4*)wq, (short4v*)wqbf, 1048576);
    cvt_bf16<<<2048, 256, 0, stream>>>((const float4*)wk, (short4v*)wkbf, 524288);
    cvt_bf16<<<2048, 256, 0, stream>>>((const float4*)wv, (short4v*)wvbf, 524288);

    // 1) Q/K/V projections (V written transposed bf16)
    qkv_mfma<<<dim3(SEQ / 128, 32), 256, 0, stream>>>(xbf, wqbf, wkbf, wvbf,
                                                      Qw, Kb, VtG);

    // 1b) wo -> bf16 (separate slot; wq slot becomes Qbf)
    cvt_bf16<<<4096, 256, 0, stream>>>((const float4*)wo, (short4v*)wobf, 1048576);

    // 2) RoPE + RMSNorm (Q fp32 -> bf16 over dead wq slot; K fp32 -> bf16)
    rope_norm_kernel<<<dim3(SEQ, 6), 256, 0, stream>>>(Qw, Kb, Qbf, KbfG, qnw, knw);

    // 3) Split-K MFMA flash attention v5 (reverted to measured-best v1 mapping)
    attn_split<<<dim3(NBX, N_HEADS), 256, 0, stream>>>(Qbf, KbfG, VtG, Opart, Ml);

    // 3b) Combine partials -> ctx bf16 (overwrites Qbf in place; attn done)
    attn_combine<<<dim3(SEQ / 8, N_HEADS), 256, 0, stream>>>(Opart, Ml, Qbf);

    // 4) Output projection: ctx @ wo^T -> d_out
    oproj_mfma<<<dim3(SEQ / 128, HIDDEN / 128), 256, 0, stream>>>(Qbf, wobf,
                                                                  (float*)d_out);
}

// Round 22
// 305.745 us; speedup vs baseline: 1.2400x; 1.2400x over previous
//
#include <hip/hip_runtime.h>
#include <hip/hip_bf16.h>

// Problem constants
#define HIDDEN   2048
#define N_HEADS  16
#define N_KV     8
#define HEAD_DIM 128
#define SEQ      2048
#define EPS      1e-6f

// MFMA GEMM tile params (m97 structure: 128x128 tile, BK=32, linear LDS)
#define BM 128
#define BN 128
#define BK 32

// MFMA attention tile params
#define ATQ 64
#define ATK 64
#define QKS 136       // Ks row stride in bf16 (128 data + 8 pad)
#define VTS 72        // Vt/Ps row stride in bf16 (64 data + 8 pad)
#define CHT 11        // K-tiles per split-K chunk (11*64 = 704 keys)
#define NBX 63        // jobs per head: 11*1 + 11*2 + 10*3 = 63

typedef __hip_bfloat16 bf16;
typedef __bf16  bf16x8 __attribute__((ext_vector_type(8)));
typedef short   short8 __attribute__((ext_vector_type(8)));
typedef short   short4v __attribute__((ext_vector_type(4)));
typedef float   f32x4  __attribute__((ext_vector_type(4)));

typedef __attribute__((address_space(1))) void gvoid;
typedef __attribute__((address_space(3))) void lvoid;

// async 16B global->LDS (direct-to-LDS DMA; dest is wave-uniform base + lane*16)
#define ASYNC16(g, l) \
    __builtin_amdgcn_global_load_lds((gvoid*)(g), (lvoid*)(l), 16, 0, 0)

__device__ __forceinline__ short f2bfbits(float x) {
    union { bf16 h; short s; } u;
    u.h = __float2bfloat16(x);
    return u.s;
}

// -------------------- fp32 -> bf16 convert (pure BW) --------------------
__global__ __launch_bounds__(256) void cvt_bf16(const float4* __restrict__ src,
                                                short4v* __restrict__ dst, int n4) {
    const int i = blockIdx.x * 256 + threadIdx.x;
    if (i >= n4) return;
    const float4 v = src[i];
    short4v p;
    p[0] = f2bfbits(v.x); p[1] = f2bfbits(v.y);
    p[2] = f2bfbits(v.z); p[3] = f2bfbits(v.w);
    dst[i] = p;
}

// -------------------- bf16 MFMA GEMM core (m97 structure) --------------------
// C[m][n] = sum_k A[m][k]*B[n][k]; A,B bf16 row-major (stride K).
// MODE 0: C fp32 row-major (stride ldc). MODE 1: C^T bf16 at Ct[n*ldc + m].
// 128x128 tile, BK=32, 256 threads (2x2 waves). Staging via global_load_lds
// width=16 into LINEAR [128][32] LDS. MFMA 16x16x32: A[m=lane&15][k=(lane>>4)*8+j];
// C/D col=lane&15, row=(lane>>4)*4+reg  [m89/m91-verified].
template <int MODE>
__device__ __forceinline__ void gemm_bf(const bf16* __restrict__ A,
                                        const bf16* __restrict__ B,
                                        float* __restrict__ C,
                                        bf16* __restrict__ Ct,
                                        int K, int ldc, int bm, int bn) {
    __shared__ __align__(16) short As[BM * BK];
    __shared__ __align__(16) short Bs[BN * BK];
    const int tid  = threadIdx.x;
    const int lane = tid & 63;
    const int wave = tid >> 6;
    const int wy   = wave & 1;
    const int wx   = wave >> 1;
    const int lrow = lane & 15;
    const int lk   = lane >> 4;
    const int srow = tid >> 2;        // staging row within a 64-row round
    const int scol = (tid & 3) * 8;   // staging col (bf16 units), 16B granules

    f32x4 acc[4][4] = {};

    for (int k0 = 0; k0 < K; k0 += BK) {
        #pragma unroll
        for (int r = 0; r < 2; r++) {
            const int row = r * 64 + srow;
            ASYNC16(&A[(size_t)(bm + row) * K + k0 + scol],
                    &As[(r * 64 + wave * 16) * BK]);
            ASYNC16(&B[(size_t)(bn + row) * K + k0 + scol],
                    &Bs[(r * 64 + wave * 16) * BK]);
        }
        __syncthreads();   // compiler drains vmcnt before s_barrier

        short8 af[4], bfr[4];
        #pragma unroll
        for (int i = 0; i < 4; i++) {
            af[i]  = *(const short8*)&As[(wy * 64 + i * 16 + lrow) * BK + lk * 8];
            bfr[i] = *(const short8*)&Bs[(wx * 64 + i * 16 + lrow) * BK + lk * 8];
        }
        #pragma unroll
        for (int i = 0; i < 4; i++)
            #pragma unroll
            for (int j = 0; j < 4; j++)
                acc[i][j] = __builtin_amdgcn_mfma_f32_16x16x32_bf16(
                    __builtin_bit_cast(bf16x8, af[i]),
                    __builtin_bit_cast(bf16x8, bfr[j]), acc[i][j], 0, 0, 0);
        __syncthreads();
    }

    #pragma unroll
    for (int i = 0; i < 4; i++)
        #pragma unroll
        for (int j = 0; j < 4; j++) {
            if (MODE == 0) {
                #pragma unroll
                for (int v = 0; v < 4; v++)
                    C[(size_t)(bm + wy * 64 + i * 16 + lk * 4 + v) * ldc
                      + bn + wx * 64 + j * 16 + lrow] = acc[i][j][v];
            } else {
                short4v pk;
                #pragma unroll
                for (int v = 0; v < 4; v++) pk[v] = f2bfbits(acc[i][j][v]);
                *(short4v*)&Ct[(size_t)(bn + wx * 64 + j * 16 + lrow) * ldc
                               + bm + wy * 64 + i * 16 + lk * 4] = pk;
            }
        }
}

// Fused Q/K/V projection: grid (16, 32). by<16 -> Q, <24 -> K, else V^T(bf16).
__global__ __launch_bounds__(256) void qkv_mfma(const bf16* __restrict__ x,
                                                const bf16* __restrict__ wq,
                                                const bf16* __restrict__ wk,
                                                const bf16* __restrict__ wv,
                                                float* __restrict__ Q,
                                                float* __restrict__ Kc,
                                                bf16* __restrict__ Vt) {
    const int by = blockIdx.y;
    const int bm = blockIdx.x * 128;
    if (by < 16)
        gemm_bf<0>(x, wq, Q, nullptr, HIDDEN, 2048, bm, by * 128);
    else if (by < 24)
        gemm_bf<0>(x, wk, Kc, nullptr, HIDDEN, 1024, bm, (by - 16) * 128);
    else
        gemm_bf<1>(x, wv, nullptr, Vt, HIDDEN, SEQ, bm, (by - 24) * 128);
}

__global__ __launch_bounds__(256) void oproj_mfma(const bf16* __restrict__ ctx,
                                                  const bf16* __restrict__ wo,
                                                  float* __restrict__ out) {
    gemm_bf<0>(ctx, wo, out, nullptr, N_HEADS * HEAD_DIM, HIDDEN,
               blockIdx.x * 128, blockIdx.y * 128);
}

// -------------------- RoPE + RMSNorm (wave-per-row, barrier-free) ------------
// Lane l owns the RoPE pair (d=l, d=l+64): same cos/sin, no cross-lane data.
// grid (S, 6), 256 threads = 4 waves; wave -> one (s, h) row, h = by*4 + wave.
__global__ __launch_bounds__(256) void rope_norm_kernel(
        const float* __restrict__ Q, const float* __restrict__ K,
        bf16* __restrict__ Qbf, bf16* __restrict__ Kbf,
        const float* __restrict__ qw, const float* __restrict__ kw) {
    const int s = blockIdx.x;
    const int h = blockIdx.y * 4 + (threadIdx.x >> 6);
    const int l = threadIdx.x & 63;

    const float* src;
    const float* w;
    if (h < N_HEADS) { src = Q + (size_t)s * (N_HEADS * HEAD_DIM) + h * HEAD_DIM; w = qw; }
    else             { src = K + (size_t)s * (N_KV * HEAD_DIM) + (h - N_HEADS) * HEAD_DIM; w = kw; }

    const float x1 = src[l];
    const float x2 = src[l + 64];
    const float inv_freq = exp2f((float)l * (-19.931568569324174f / 64.0f));
    const float ang = (float)s * inv_freq;
    float sn, cs;
    __sincosf(ang, &sn, &cs);
    float r1 = x1 * cs - x2 * sn;
    float r2 = x2 * cs + x1 * sn;

    float ss = r1 * r1 + r2 * r2;
    #pragma unroll
    for (int off = 1; off < 64; off <<= 1)
        ss += __shfl_xor(ss, off, 64);
    const float rs = rsqrtf(ss / 128.0f + EPS);

    if (h < N_HEADS) {
        bf16* dst = Qbf + ((size_t)s * N_HEADS + h) * HEAD_DIM;
        dst[l]      = __float2bfloat16(w[l] * r1 * rs);
        dst[l + 64] = __float2bfloat16(w[l + 64] * r2 * rs);
    } else {
        bf16* dst = Kbf + ((size_t)s * N_KV + (h - N_HEADS)) * HEAD_DIM;
        dst[l]      = __float2bfloat16(w[l] * r1 * rs);
        dst[l + 64] = __float2bfloat16(w[l + 64] * r2 * rs);
    }
}

// -------------------- MFMA flash attention, split-K v6 -----------------------
// v1's EXACT measured body (5.3us/iter: mask every tile, per-iter shuffle
// l-reduce; 76 VGPR) + v4's LPT CHT=11 mapping (measured 11.3-iter makespan,
// h-fastest FETCH halving). Model dur = cost/iter x makespan explains all 5
// prior runs: v1 5.3x16=85, v3 8.6x11.6=100, v4 8.6x11.3=97, v5 8.6x16=138.
// The v3 "micro-opts" (diagonal branch, deferred l-sum) WERE the per-iter
// regression (v5 proved it: same mapping as v1, +63%). Predicted: 5.3x11.3
// ~= 60-68us.
__global__ __launch_bounds__(256) void attn_split(const bf16* __restrict__ QC,
                                                  const bf16* __restrict__ KbfG,
                                                  const bf16* __restrict__ VtG,
                                                  float* __restrict__ Opart,
                                                  float* __restrict__ Ml) {
    const int h = blockIdx.x;         // head fastest -> LPT order across heads
    const int j = blockIdx.y;         // job rank, descending iteration count
    int qtile, ci;
    if (j == 0)       { qtile = 10;          ci = 0; }   // 11 iters
    else if (j <= 11) { qtile = 11 + (j - 1);  ci = 0; } // 11 iters (2-chunk c0)
    else if (j == 12) { qtile = 21;          ci = 1; }   // 11 iters
    else if (j <= 22) { qtile = 22 + (j - 13); ci = 0; } // 11 iters (3-chunk c0)
    else if (j <= 32) { qtile = 22 + (j - 23); ci = 1; } // 11 iters (3-chunk c1)
    else {                                              // k = 10..1 iters, 3 each
        const int g = (j - 33) / 3, r = (j - 33) % 3, k = 10 - g;
        if (r == 0)      { qtile = k - 1;  ci = 0; }
        else if (r == 1) { qtile = 10 + k; ci = 1; }
        else             { qtile = 21 + k; ci = 2; }
    }
    // canonical slot index (attn_combine's layout)
    int bxc;
    if (qtile < 11)      bxc = qtile;
    else if (qtile < 22) bxc = 11 + 2 * (qtile - 11) + ci;
    else                 bxc = 33 + 3 * (qtile - 22) + ci;

    const int t0 = ci * CHT;
    const int t1 = min(t0 + CHT - 1, qtile);
    const int q0    = qtile * ATQ;
    const int kvh   = h >> 1;
    const int tid   = threadIdx.x;
    const int lane  = tid & 63;
    const int w     = tid >> 6;
    const int lrow  = lane & 15;
    const int lk    = lane >> 4;     // quad
    const float scale = 0.08838834764831845f;

    __shared__ short Ks[ATK * QKS];
    __shared__ short Vt[HEAD_DIM * VTS];
    __shared__ short Ps[ATQ * VTS];

    f32x4 O[8] = {};
    float m_run[4] = {-1e30f, -1e30f, -1e30f, -1e30f};
    float l_run[4] = {};

    // Q frags straight to registers (bf16)
    short8 aq[4];
    {
        const bf16* qrow =
            &QC[(size_t)(q0 + w * 16 + lrow) * (N_HEADS * HEAD_DIM) + h * HEAD_DIM];
        #pragma unroll
        for (int kc = 0; kc < 4; kc++)
            aq[kc] = *(const short8*)&qrow[kc * 32 + lk * 8];
    }

    for (int t = t0; t <= t1; t++) {
        const int k0 = t * ATK;
        // stage K and Vt (bf16 copies; shared by all 4 waves)
        for (int idx = tid; idx < ATK * 16; idx += 256) {
            const int r = idx >> 4, c8 = idx & 15;
            *(short8*)&Ks[r * QKS + c8 * 8] = *(const short8*)
                &KbfG[((size_t)(k0 + r) * N_KV + kvh) * HEAD_DIM + c8 * 8];
        }
        for (int idx = tid; idx < HEAD_DIM * 8; idx += 256) {
            const int d = idx >> 3, ck = idx & 7;
            *(short8*)&Vt[d * VTS + ck * 8] =
                *(const short8*)&VtG[((size_t)kvh * HEAD_DIM + d) * SEQ + k0 + ck * 8];
        }
        __syncthreads();

        // QK^T: S (16q x 64k) per wave
        f32x4 s[4] = {};
        #pragma unroll
        for (int nt = 0; nt < 4; nt++)
            #pragma unroll
            for (int kc = 0; kc < 4; kc++) {
                const short8 bk = *(const short8*)
                    &Ks[(nt * 16 + lrow) * QKS + kc * 32 + lk * 8];
                s[nt] = __builtin_amdgcn_mfma_f32_16x16x32_bf16(
                    __builtin_bit_cast(bf16x8, aq[kc]),
                    __builtin_bit_cast(bf16x8, bk), s[nt], 0, 0, 0);
            }

        // online softmax (rows q = q0 + 16w + 4*lk + r) -- exact v1 body
        float p[4][4];
        float mloc[4] = {-1e30f, -1e30f, -1e30f, -1e30f};
        #pragma unroll
        for (int nt = 0; nt < 4; nt++) {
            const int kglob = k0 + nt * 16 + lrow;
            #pragma unroll
            for (int r = 0; r < 4; r++) {
                float v = s[nt][r] * scale;
                v = (kglob <= q0 + w * 16 + lk * 4 + r) ? v : -1e30f;
                p[nt][r] = v;
                mloc[r] = fmaxf(mloc[r], v);
            }
        }
        #pragma unroll
        for (int off = 1; off < 16; off <<= 1)
            #pragma unroll
            for (int r = 0; r < 4; r++)
                mloc[r] = fmaxf(mloc[r], __shfl_xor(mloc[r], off, 64));

        float alpha[4], ls[4];
        #pragma unroll
        for (int r = 0; r < 4; r++) {
            const float mnew = fmaxf(m_run[r], mloc[r]);
            alpha[r] = __expf(m_run[r] - mnew);
            m_run[r] = mnew;
            ls[r] = 0.f;
        }
        #pragma unroll
        for (int nt = 0; nt < 4; nt++)
            #pragma unroll
            for (int r = 0; r < 4; r++) {
                const float e = __expf(p[nt][r] - m_run[r]);
                Ps[(w * 16 + lk * 4 + r) * VTS + nt * 16 + lrow] = f2bfbits(e);
                ls[r] += e;
            }
        #pragma unroll
        for (int off = 1; off < 16; off <<= 1)
            #pragma unroll
            for (int r = 0; r < 4; r++)
                ls[r] += __shfl_xor(ls[r], off, 64);
        #pragma unroll
        for (int r = 0; r < 4; r++)
            l_run[r] = l_run[r] * alpha[r] + ls[r];
        #pragma unroll
        for (int dnt = 0; dnt < 8; dnt++)
            #pragma unroll
            for (int r = 0; r < 4; r++)
                O[dnt][r] *= alpha[r];

        __syncthreads();   // Ps visible

        // PV: O (16q x 128d) += P (16x64) * V (64x128)
        short8 pa[2];
        #pragma unroll
        for (int ks = 0; ks < 2; ks++)
            pa[ks] = *(const short8*)&Ps[(w * 16 + lrow) * VTS + ks * 32 + lk * 8];
        #pragma unroll
        for (int dnt = 0; dnt < 8; dnt++)
            #pragma unroll
            for (int ks = 0; ks < 2; ks++) {
                const short8 vb = *(const short8*)
                    &Vt[(dnt * 16 + lrow) * VTS + ks * 32 + lk * 8];
                O[dnt] = __builtin_amdgcn_mfma_f32_16x16x32_bf16(
                    __builtin_bit_cast(bf16x8, pa[ks]),
                    __builtin_bit_cast(bf16x8, vb), O[dnt], 0, 0, 0);
            }
        __syncthreads();   // tiles consumed before next staging
    }

    // epilogue: write UNNORMALIZED partial O (fp32) + (m,l) per row
    const int slot = h * NBX + bxc;
    #pragma unroll
    for (int r = 0; r < 4; r++) {
        const int row = w * 16 + lk * 4 + r;
        float* orow = &Opart[(size_t)slot * (ATQ * HEAD_DIM) + row * HEAD_DIM];
        #pragma unroll
        for (int dnt = 0; dnt < 8; dnt++)
            orow[dnt * 16 + lrow] = O[dnt][r];
        if (lrow == 0) {
            Ml[slot * (ATQ * 2) + row * 2]     = m_run[r];
            Ml[slot * (ATQ * 2) + row * 2 + 1] = l_run[r];
        }
    }
}

// Combine 1..3 chunks per (h, s-row), normalize, write ctx bf16 into Qbf.
// grid (256, 16): block handles 8 s-rows; 32 lanes/row, float4 per lane.
__global__ __launch_bounds__(256) void attn_combine(const float* __restrict__ Opart,
                                                    const float* __restrict__ Ml,
                                                    bf16* __restrict__ Qbf) {
    const int h   = blockIdx.y;
    const int s   = blockIdx.x * 8 + (threadIdx.x >> 5);
    const int d   = (threadIdx.x & 31) * 4;
    const int qt  = s >> 6;
    const int row = s & 63;

    int slot0, nch;
    if (qt < 11)      { slot0 = qt;               nch = 1; }
    else if (qt < 22) { slot0 = 11 + 2 * (qt - 11); nch = 2; }
    else              { slot0 = 33 + 3 * (qt - 22); nch = 3; }
    slot0 += h * NBX;

    float M = Ml[slot0 * (ATQ * 2) + row * 2];
    float L = Ml[slot0 * (ATQ * 2) + row * 2 + 1];
    float4 o = *(const float4*)&Opart[(size_t)slot0 * (ATQ * HEAD_DIM)
                                      + row * HEAD_DIM + d];
    for (int c = 1; c < nch; c++) {
        const float mc = Ml[(slot0 + c) * (ATQ * 2) + row * 2];
        const float lc = Ml[(slot0 + c) * (ATQ * 2) + row * 2 + 1];
        const float4 oc = *(const float4*)&Opart[(size_t)(slot0 + c) * (ATQ * HEAD_DIM)
                                                 + row * HEAD_DIM + d];
        const float Mn = fmaxf(M, mc);
        const float e0 = __expf(M - Mn);
        const float e1 = __expf(mc - Mn);
        L = L * e0 + lc * e1;
        o.x = o.x * e0 + oc.x * e1;
        o.y = o.y * e0 + oc.y * e1;
        o.z = o.z * e0 + oc.z * e1;
        o.w = o.w * e0 + oc.w * e1;
        M = Mn;
    }
    const float inv = 1.0f / L;
    short4v pk;
    pk[0] = f2bfbits(o.x * inv); pk[1] = f2bfbits(o.y * inv);
    pk[2] = f2bfbits(o.z * inv); pk[3] = f2bfbits(o.w * inv);
    *(short4v*)&Qbf[((size_t)s * N_HEADS + h) * HEAD_DIM + d] = pk;
}

extern "C" void kernel_launch(void* const* d_in, const int* in_sizes, int n_in,
                              void* d_out, int out_size, void* d_ws, size_t ws_size,
                              hipStream_t stream) {
    const float* x   = (const float*)d_in[0]; // [S][HIDDEN] fp32
    const float* wq  = (const float*)d_in[3]; // [2048][2048]
    const float* wk  = (const float*)d_in[4]; // [1024][2048]
    const float* wv  = (const float*)d_in[5]; // [1024][2048]
    const float* wo  = (const float*)d_in[6]; // [2048][2048]
    const float* qnw = (const float*)d_in[7]; // [128]
    const float* knw = (const float*)d_in[8]; // [128]

    // Memory plan (ws >= 48MB):
    //   ws  [ 0,16): Q fp32 proj output (dead after rope)  }
    //   ws  [16,24): x bf16 (dead after qkv)               } Opart 31.5MB
    //   ws  [24,28): wk bf16 (dead after qkv)              } at attn time
    //   ws  [28,32): wv bf16 (dead after qkv)              }
    //   ws  [32,40): wq bf16 (dead after qkv) -> Qbf post-rope [S][16][128];
    //                ctx bf16 overwrites in place (combine output)
    //   ws  [40,48): wo bf16 (cvt after qkv; LIVE through oproj)
    //   d_out[0, 8): K fp32 pre-rope (dead after rope) -> Ml (516KB) at attn
    //   d_out[8,12): V^T bf16 [8*128][2048]  } dead before oproj
    //   d_out[12,16): K bf16 post-rope       } oproj output overwrites d_out
    char*  ws    = (char*)d_ws;
    float* Qw    = (float*)ws;
    bf16*  xbf   = (bf16*)(ws + (16u << 20));
    bf16*  wkbf  = (bf16*)(ws + (24u << 20));
    bf16*  wvbf  = (bf16*)(ws + (28u << 20));
    bf16*  wqbf  = (bf16*)(ws + (32u << 20));
    bf16*  Qbf   = (bf16*)(ws + (32u << 20));   // over dead wqbf
    bf16*  wobf  = (bf16*)(ws + (40u << 20));
    float* Opart = (float*)ws;                  // 1008 * 32KB = 31.5MB in [0,32)
    float* Kb    = (float*)d_out;
    float* Ml    = (float*)d_out;               // 516KB over dead Kb
    bf16*  VtG   = (bf16*)((char*)d_out + (8u << 20));
    bf16*  KbfG  = (bf16*)((char*)d_out + (12u << 20));

    // 0) fp32 -> bf16 converts (x + qkv weights)
    cvt_bf16<<<4096, 256, 0, stream>>>((const float4*)x,  (short4v*)xbf,  1048576);
    cvt_bf16<<<4096, 256, 0, stream>>>((const float4*)wq, (short4v*)wqbf, 1048576);
    cvt_bf16<<<2048, 256, 0, stream>>>((const float4*)wk, (short4v*)wkbf, 524288);
    cvt_bf16<<<2048, 256, 0, stream>>>((const float4*)wv, (short4v*)wvbf, 524288);

    // 1) Q/K/V projections (V written transposed bf16)
    qkv_mfma<<<dim3(SEQ / 128, 32), 256, 0, stream>>>(xbf, wqbf, wkbf, wvbf,
                                                      Qw, Kb, VtG);

    // 1b) wo -> bf16 (separate slot; wq slot becomes Qbf)
    cvt_bf16<<<4096, 256, 0, stream>>>((const float4*)wo, (short4v*)wobf, 1048576);

    // 2) RoPE + RMSNorm (Q fp32 -> bf16 over dead wq slot; K fp32 -> bf16)
    rope_norm_kernel<<<dim3(SEQ, 6), 256, 0, stream>>>(Qw, Kb, Qbf, KbfG, qnw, knw);

    // 3) Split-K MFMA flash attention v6 (v1 body + LPT CHT=11 mapping)
    attn_split<<<dim3(N_HEADS, NBX), 256, 0, stream>>>(Qbf, KbfG, VtG, Opart, Ml);

    // 3b) Combine partials -> ctx bf16 (overwrites Qbf in place; attn done)
    attn_combine<<<dim3(SEQ / 8, N_HEADS), 256, 0, stream>>>(Opart, Ml, Qbf);

    // 4) Output projection: ctx @ wo^T -> d_out
    oproj_mfma<<<dim3(SEQ / 128, HIDDEN / 128), 256, 0, stream>>>(Qbf, wobf,
                                                                  (float*)d_out);
}